// Round 1
// 118.242 us; speedup vs baseline: 1.0836x; 1.0836x over previous
//
#include <hip/hip_runtime.h>

// CQT on gfx950 — v8: fused W-precompute with on-the-fly trig (no tables, no Pp).
//   Wr[b,n] = sum_k kr[b,k]*wcos[k,n] - ki[b,k]*wsin[k,n]
//   Wi[b,n] = sum_k kr[b,k]*wsin[k,n] + ki[b,k]*wcos[k,n]
//   cqt[b,f] = sqrt((sum_n x[512f+n]*W[2b,n])^2 + (sum_n x[512f+n]*W[2b+1,n])^2)
// K1 aprep:   Apf = A'[192][2208] bf16 in MFMA-frag order [mt][k16][lane]x8.
//             A' row 2b=[kr_b | -ki_b], 2b+1=[ki_b | kr_b] (cos k<=1024, sin 1025..2049).
//             (v8: single uint4 store per thread instead of 8 ushort stores.)
// K2 wfused:  W = A' x Trig directly -> Wpf bf16 in frag order. B-matrix generated
//             in-register: phase = (k*n) mod 2048 exact in int, v_cos/v_sin on
//             revolutions. Swapped operands: D = mfma(Trig^T, A'^T) = W^T, lane owns
//             W-row = c32 -> direct frag-order stores (4x 8B per lane, coalesced).
//             384 blocks x 4 waves; K split 33/33/33/30 k16-slots; LDS reduce.
//             Replaces old wgemm(2304 1-wave blocks)+combine and the 18.9 MB Pp
//             round-trip; wcos/wsin never touched (16.8 MB fetch + ~150 MB LLC
//             traffic eliminated). Trig error ~1e-7 << bf16 rounding already applied
//             to table values in v7, so numerics are unchanged at bf16 granularity.
// K3 cqt:     (unchanged v7) block 192rows x 64frames, 12 waves (6mg x 2fg, 32x32
//             tiles), x-span staged once to LDS (barrier-free K-loop), A from Wpf
//             coalesced with 8-deep double-buffered register prefetch.

#define HOPS 512
#define NBINS 84
#define FREQB 1025
#define NFRAMES 16381
#define TSAMP 8388608
#define SPAN 34304            // 63*512 + 2048
#define XLSZ 34572            // SPAN + 4*(SPAN/512) pads
#define KP16 138              // k16 slots in A' K dim (2208)

typedef short bf16x8 __attribute__((ext_vector_type(8)));
typedef float f32x16 __attribute__((ext_vector_type(16)));

union B8 { struct { ushort4 lo, hi; } p; bf16x8 v; uint4 u; };

__device__ __forceinline__ unsigned short f32_to_bf16(float f) {
    union { float f; unsigned u; } v; v.f = f;
    return (unsigned short)((v.u + 0x7FFFu + ((v.u >> 16) & 1u)) >> 16);
}
__device__ __forceinline__ unsigned pk_bf16(float lo, float hi) {
    return (unsigned)f32_to_bf16(lo) | ((unsigned)f32_to_bf16(hi) << 16);
}
__device__ __forceinline__ bf16x8 pack8(const float* s) {
    B8 r;
    r.u.x = pk_bf16(s[0], s[1]); r.u.y = pk_bf16(s[2], s[3]);
    r.u.z = pk_bf16(s[4], s[5]); r.u.w = pk_bf16(s[6], s[7]);
    return r.v;
}

// cos/sin with input in revolutions (maps to v_cos_f32 / v_sin_f32)
__device__ __forceinline__ float cos_rev(float r) { return __builtin_amdgcn_cosf(r); }
__device__ __forceinline__ float sin_rev(float r) { return __builtin_amdgcn_sinf(r); }

// ---------------- K1: A' prep into frag order ----------------
// grid 828 x 64: bid = mt*138 + k16. lane l: c32=l&31, h=l>>5.
// Apf[(mt*138+k16)*512 + l*8 + j] = A'[mt*32+c32][k16*16+h*8+j]
__global__ __launch_bounds__(64) void aprep_kernel(
    const float* __restrict__ kr, const float* __restrict__ ki,
    unsigned short* __restrict__ Apf)
{
    const int bid = blockIdx.x;
    const int mt = bid / KP16, k16 = bid % KP16;
    const int l = threadIdx.x;
    const int c32 = l & 31, h = l >> 5;
    const int row = mt * 32 + c32;
    const int b = row >> 1, im = row & 1;
    const bool bok = b < NBINS;
    const float* cosp = (im ? ki : kr) + (size_t)(bok ? b : 0) * FREQB;
    const float* sinp = (im ? kr : ki) + (size_t)(bok ? b : 0) * FREQB;
    const float ssign = im ? 1.f : -1.f;

    unsigned short o[8];
    #pragma unroll
    for (int j = 0; j < 8; ++j) {
        int k = k16 * 16 + h * 8 + j;
        float v = 0.f;
        if (bok) {
            if (k <= 1024)       v = cosp[k];
            else if (k <= 2049)  v = ssign * sinp[k - 1025];
        }
        o[j] = f32_to_bf16(v);
    }
    uint4 pk;
    pk.x = (unsigned)o[0] | ((unsigned)o[1] << 16);
    pk.y = (unsigned)o[2] | ((unsigned)o[3] << 16);
    pk.z = (unsigned)o[4] | ((unsigned)o[5] << 16);
    pk.w = (unsigned)o[6] | ((unsigned)o[7] << 16);
    *(uint4*)(Apf + (size_t)bid * 512 + (size_t)l * 8) = pk;
}

// ---------------- K2: fused W GEMM -> Wpf (frag order, bf16) ----------------
// grid 384 x 256: mt = bid>>6 (0..5), nt = bid&63. 4 waves split K (129 k16 slots).
// Swapped mfma: D = Trig^T(32n x 16k) * A'^T(16k x 32row) = W^T tile.
//   A-operand lane (c32,h): Trig[n=nt*32+c32][k-run k16*16+h*8+j] (generated).
//   B-operand lane (c32,h): A'[mt*32+c32][same k-run] = Apf frag (unchanged layout).
// D layout: lane col c32 = W-row-in-tile; D-row (=n_tile) = (r&3)+8*(r>>2)+4h.
// Frag store per quad g=r>>2: Wpf[(mt*128 + nt*2 + (g>>1))*512
//                                 + (c32 + 32*(g&1))*8 + 4*h + (r&3)]
__global__ __launch_bounds__(256) void wfused_kernel(
    const unsigned short* __restrict__ Apf, unsigned short* __restrict__ Wpf)
{
    __shared__ float4 red[3][4][64];   // 12 KB cross-wave reduce

    const int bid = blockIdx.x;
    const int mt = bid >> 6, nt = bid & 63;
    const int t = threadIdx.x;
    const int w = t >> 6, l = t & 63;
    const int c32 = l & 31, h = l >> 5;
    const int n = nt * 32 + c32;

    f32x16 acc;
    #pragma unroll
    for (int i = 0; i < 16; ++i) acc[i] = 0.f;

    const int k0 = w * 33;
    const int kcnt = (w < 3) ? 33 : 30;   // covers k16 = 0..128 (k up to 2049 nonzero)
    const unsigned short* ap = Apf + (size_t)(mt * KP16 + k0) * 512 + (size_t)l * 8;

    for (int i = 0; i < kcnt; ++i) {
        const int k16 = k0 + i;
        B8 bf; bf.u = *(const uint4*)(ap + (size_t)i * 512);
        float tv[8];
        const int kb = k16 * 16 + h * 8;
        if (k16 <= 63) {                       // pure cos rows
            #pragma unroll
            for (int j = 0; j < 8; ++j) {
                int p = __mul24(kb + j, n) & 2047;
                tv[j] = cos_rev((float)p * (1.f / 2048.f));
            }
        } else if (k16 >= 65 && k16 <= 127) {  // pure sin rows (m = k-1025)
            #pragma unroll
            for (int j = 0; j < 8; ++j) {
                int p = __mul24(kb + j - 1025, n) & 2047;
                tv[j] = sin_rev((float)p * (1.f / 2048.f));
            }
        } else {                               // mixed k16==64 or 128 (+ zero tail)
            #pragma unroll
            for (int j = 0; j < 8; ++j) {
                int k = kb + j;
                float v = 0.f;
                if (k <= 1024) {
                    int p = __mul24(k, n) & 2047;
                    v = cos_rev((float)p * (1.f / 2048.f));
                } else if (k <= 2049) {
                    int p = __mul24(k - 1025, n) & 2047;
                    v = sin_rev((float)p * (1.f / 2048.f));
                }
                tv[j] = v;
            }
        }
        acc = __builtin_amdgcn_mfma_f32_32x32x16_bf16(pack8(tv), bf.v, acc, 0, 0, 0);
    }

    if (w > 0) {
        #pragma unroll
        for (int q = 0; q < 4; ++q)
            red[w - 1][q][l] = make_float4(acc[4*q+0], acc[4*q+1], acc[4*q+2], acc[4*q+3]);
    }
    __syncthreads();
    if (w == 0) {
        #pragma unroll
        for (int s = 0; s < 3; ++s) {
            #pragma unroll
            for (int q = 0; q < 4; ++q) {
                float4 v = red[s][q][l];
                acc[4*q+0] += v.x; acc[4*q+1] += v.y;
                acc[4*q+2] += v.z; acc[4*q+3] += v.w;
            }
        }
        #pragma unroll
        for (int g = 0; g < 4; ++g) {
            uint2 qo;
            qo.x = pk_bf16(acc[4*g+0], acc[4*g+1]);
            qo.y = pk_bf16(acc[4*g+2], acc[4*g+3]);
            size_t off = (size_t)(mt * 128 + nt * 2 + (g >> 1)) * 512
                       + (size_t)(c32 + 32 * (g & 1)) * 8 + 4 * h;
            *(uint2*)(Wpf + off) = qo;   // 8B, coalesced 512B per (wave,g)
        }
    }
}

// ---------------- K3: main GEMM, barrier-free, deep prefetch ----------------
// grid 256 x 768. Block: frames f0..f0+63, all 192 rows. 12 waves: mg=w>>1 (32 rows),
// fg=w&1 (32 frames). mfma 32x32x16, acc 16. A from Wpf (frag order, coalesced),
// 8-step double-buffered register prefetch. B from xl LDS (pad 4/512, b64 pairs).
__global__ __launch_bounds__(768) void cqt_kernel(
    const float* __restrict__ x, const unsigned short* __restrict__ Wpf,
    float* __restrict__ out)
{
    __shared__ __align__(16) unsigned short xl[XLSZ];   // 69,144 B

    const int t = threadIdx.x;
    const int f0 = blockIdx.x * 64;
    const long S0 = (long)f0 * HOPS;
    const int valid = (int)((TSAMP - S0) < (long)SPAN ? (TSAMP - S0) : (long)SPAN);

    // stage x-span once: 8576 float4 over 768 threads
    #pragma unroll
    for (int i = 0; i < 12; ++i) {
        int idx4 = t + i * 768;
        if (idx4 < 8576) {
            int s = idx4 * 4;
            float4 v = make_float4(0.f, 0.f, 0.f, 0.f);
            if (s + 4 <= valid) v = *(const float4*)(x + S0 + s);
            ushort4 o;
            o.x = f32_to_bf16(v.x); o.y = f32_to_bf16(v.y);
            o.z = f32_to_bf16(v.z); o.w = f32_to_bf16(v.w);
            *(ushort4*)(&xl[s + 4 * (s >> 9)]) = o;
        }
    }
    __syncthreads();   // the only barrier

    const int w = t >> 6, l = t & 63;
    const int mg = w >> 1, fg = w & 1;
    const int c32 = l & 31, h = l >> 5;

    const unsigned short* apf = Wpf + (size_t)mg * (128 * 512) + l * 8;  // +k16*512
    const int sbase = (fg * 32 + c32) * HOPS + h * 8;

    f32x16 acc;
    #pragma unroll
    for (int i = 0; i < 16; ++i) acc[i] = 0.f;

    auto ldsB = [&](int k16) -> bf16x8 {
        int s = sbase + k16 * 16;
        int off = s + 4 * (s >> 9);
        B8 r;
        r.p.lo = *(const ushort4*)(&xl[off]);
        r.p.hi = *(const ushort4*)(&xl[off + 4]);
        return r.v;
    };

    uint4 Abuf[2][8];
    #pragma unroll
    for (int j = 0; j < 8; ++j)
        Abuf[0][j] = *(const uint4*)(apf + (size_t)j * 512);

    #pragma unroll
    for (int c = 0; c < 16; ++c) {
        const int cur = c & 1, nxt = cur ^ 1;
        if (c < 15) {
            #pragma unroll
            for (int j = 0; j < 8; ++j)
                Abuf[nxt][j] = *(const uint4*)(apf + (size_t)((c + 1) * 8 + j) * 512);
        }
        #pragma unroll
        for (int j = 0; j < 8; ++j) {
            B8 af; af.u = Abuf[cur][j];
            acc = __builtin_amdgcn_mfma_f32_32x32x16_bf16(af.v, ldsB(c * 8 + j), acc, 0, 0, 0);
        }
    }

    // epilogue: C/D col=c32 (f), row=(r&3)+8*(r>>2)+4*h; (Wr,Wi) pairs -> magnitude
    const int f = f0 + fg * 32 + c32;
    if (f < NFRAMES) {
        #pragma unroll
        for (int rp = 0; rp < 4; ++rp) {
            int base = mg * 32 + 8 * rp + 4 * h;   // even
            int b0 = base >> 1;
            float r0 = acc[4 * rp + 0], i0 = acc[4 * rp + 1];
            float r1 = acc[4 * rp + 2], i1 = acc[4 * rp + 3];
            if (b0 < NBINS)
                out[(size_t)b0 * NFRAMES + f] = sqrtf(r0 * r0 + i0 * i0);
            if (b0 + 1 < NBINS)
                out[(size_t)(b0 + 1) * NFRAMES + f] = sqrtf(r1 * r1 + i1 * i1);
        }
    }
}

extern "C" void kernel_launch(void* const* d_in, const int* in_sizes, int n_in,
                              void* d_out, int out_size, void* d_ws, size_t ws_size,
                              hipStream_t stream) {
    const float* x    = (const float*)d_in[0];
    // d_in[1] (wcos) and d_in[2] (wsin) no longer read — trig generated on-device.
    const float* kr   = (const float*)d_in[3];
    const float* ki   = (const float*)d_in[4];
    float* out = (float*)d_out;

    unsigned short* Wpf = (unsigned short*)d_ws;                    // 786,432 B
    unsigned short* Apf = (unsigned short*)((char*)d_ws + 786432);  // 847,872 B

    aprep_kernel<<<dim3(6 * KP16), dim3(64), 0, stream>>>(kr, ki, Apf);
    wfused_kernel<<<dim3(384), dim3(256), 0, stream>>>(Apf, Wpf);
    cqt_kernel<<<dim3(256), dim3(768), 0, stream>>>(x, Wpf, out);
}